// Round 1
// baseline (149.061 us; speedup 1.0000x reference)
//
#include <hip/hip_runtime.h>
#include <math.h>

typedef __attribute__((ext_vector_type(8))) short bf16x8;
typedef _Float16 f16x8 __attribute__((ext_vector_type(8)));
typedef __attribute__((ext_vector_type(4))) float f32x4;

#define PI_F 3.14159265358979323846f

__device__ __forceinline__ unsigned short f2bf(float f) {
  unsigned int u = __float_as_uint(f);
  u += 0x7FFFu + ((u >> 16) & 1u);   // RNE to bf16
  return (unsigned short)(u >> 16);
}

__device__ __forceinline__ float bf2f(unsigned short u) {
  return __uint_as_float(((unsigned int)u) << 16);
}

__device__ __forceinline__ void async_ld16(const unsigned short* g, unsigned short* l) {
  __builtin_amdgcn_global_load_lds(
      (const __attribute__((address_space(1))) void*)g,
      (__attribute__((address_space(3))) void*)l,
      16, 0, 0);
}

// fast erf, A&S 7.1.26, |err| <= 1.5e-7 absolute
__device__ __forceinline__ float fast_erf(float x) {
  float a = fabsf(x);
  float t = 1.0f / fmaf(0.3275911f, a, 1.0f);
  float p = t * fmaf(t, fmaf(t, fmaf(t, fmaf(t, 1.061405429f, -1.453152027f),
                                     1.421413741f), -0.284496736f), 0.254829592f);
  float e = __expf(-a * a);
  float r = 1.0f - p * e;
  return copysignf(r, x);
}

__device__ __forceinline__ float fast_tanh(float a) {
  float e = __expf(2.0f * a);
  return 1.0f - 2.0f / (e + 1.0f);
}

// RX on stored basis: XOR-pair (lane-mask ML, register-mask MR); RX matrix symmetric.
template<int ML, int MR>
__device__ __forceinline__ void apply_rx(float re[4], float im[4], float c, float s) {
  float pr[4], pi[4];
  #pragma unroll
  for (int r = 0; r < 4; r++) {
    float vr = re[r ^ MR], vi = im[r ^ MR];
    if (ML) { vr = __shfl_xor(vr, ML, 64); vi = __shfl_xor(vi, ML, 64); }
    pr[r] = vr; pi[r] = vi;
  }
  #pragma unroll
  for (int r = 0; r < 4; r++) {
    re[r] = fmaf(c, re[r],  s * pi[r]);
    im[r] = fmaf(c, im[r], -s * pr[r]);
  }
}

// fold-reduce 8 values across 64 lanes: 10 shuffles. On exit v[0] of lane L holds
// the wave-sum of value w(L) = 4*(L&1) + (L&2) + ((L>>2)&1).
__device__ __forceinline__ void fold_reduce8(float v[8], int L) {
  #pragma unroll
  for (int step = 0; step < 3; step++) {
    int d = 1 << step;
    int half = 4 >> step;
    bool hi = (L & d) != 0;
    #pragma unroll
    for (int w = 0; w < half; w++) {
      float send = hi ? v[w] : v[w + half];
      float recv = __shfl_xor(send, d, 64);
      v[w] = (hi ? v[w + half] : v[w]) + recv;
    }
  }
  v[0] += __shfl_xor(v[0], 8, 64);
  v[0] += __shfl_xor(v[0], 16, 64);
  v[0] += __shfl_xor(v[0], 32, 64);
}

// ---------------- prep: adj/Wg cvt, U-builder (interleaved), G-builder, x transpose ----
// blocks [0,1024): adj cvt; [1024,1088): Wg cvt; [1088,1152): U-builder;
// [1152,1168): G-builder; [1168,5264): x transpose (16,1024,256)->(4096,1024) bf16.
__global__ __launch_bounds__(256)
void prep_kernel(const float* __restrict__ adj, unsigned short* __restrict__ adj_bf,
                 const float* __restrict__ Wg, unsigned short* __restrict__ Wg_bf,
                 const float* __restrict__ qw, unsigned short* __restrict__ Uri,
                 const float* __restrict__ Wpost, _Float16* __restrict__ Gt,
                 const float* __restrict__ x, unsigned short* __restrict__ xT) {
  __shared__ float smem[1056];
  int bid = blockIdx.x, t = threadIdx.x;
  if (bid < 1024) {
    int i = bid * 256 + t;
    float4 v = ((const float4*)adj)[i];
    ushort4 o; o.x = f2bf(v.x); o.y = f2bf(v.y); o.z = f2bf(v.z); o.w = f2bf(v.w);
    ((ushort4*)adj_bf)[i] = o;
  } else if (bid < 1088) {
    int i = (bid - 1024) * 256 + t;
    float4 v = ((const float4*)Wg)[i];
    ushort4 o; o.x = f2bf(v.x); o.y = f2bf(v.y); o.z = f2bf(v.z); o.w = f2bf(v.w);
    ((ushort4*)Wg_bf)[i] = o;
  } else if (bid < 1152) {
    // U-builder: simulate entangler on basis k. CNOT rings deferred (linear maps);
    // layer-2 RX masks = R^-1 e_w; logical index n = R^2 s (rows of R^2 below).
    // Output layout INTERLEAVED by 16-blocks: row (n>>4)*32 + (n&15)      = Ure[n][*]
    //                                         row (n>>4)*32 + 16 + (n&15) = Uim[n][*]
    if (t < 16) { smem[t] = cosf(0.5f * qw[t]); smem[16 + t] = sinf(0.5f * qw[t]); }
    __syncthreads();
    int wv = t >> 6, L = t & 63;
    int k = (bid - 1088) * 4 + wv;
    float re[4], im[4];
    #pragma unroll
    for (int r = 0; r < 4; r++) { re[r] = (r * 64 + L == k) ? 1.f : 0.f; im[r] = 0.f; }
    // layer 1 RX (F = I)
    apply_rx<1, 0>(re, im, smem[0], smem[16]);
    apply_rx<2, 0>(re, im, smem[1], smem[17]);
    apply_rx<4, 0>(re, im, smem[2], smem[18]);
    apply_rx<8, 0>(re, im, smem[3], smem[19]);
    apply_rx<16, 0>(re, im, smem[4], smem[20]);
    apply_rx<32, 0>(re, im, smem[5], smem[21]);
    apply_rx<0, 1>(re, im, smem[6], smem[22]);
    apply_rx<0, 2>(re, im, smem[7], smem[23]);
    // layer 2 RX (F = R): masks R^-1 e_w
    apply_rx<3, 0>(re, im, smem[8], smem[24]);
    apply_rx<6, 0>(re, im, smem[9], smem[25]);
    apply_rx<12, 0>(re, im, smem[10], smem[26]);
    apply_rx<24, 0>(re, im, smem[11], smem[27]);
    apply_rx<48, 0>(re, im, smem[12], smem[28]);
    apply_rx<32, 1>(re, im, smem[13], smem[29]);
    apply_rx<0, 3>(re, im, smem[14], smem[30]);
    apply_rx<3, 2>(re, im, smem[15], smem[31]);
    const int M[8] = {0xAB, 0xFD, 0xFA, 0xF5, 0xEA, 0xD5, 0xAA, 0x55};
    #pragma unroll
    for (int r = 0; r < 4; r++) {
      int n = 0;
      #pragma unroll
      for (int w = 0; w < 8; w++) {
        int bit = (__popc(L & (M[w] & 63)) ^ __popc((r << 6) & M[w])) & 1;
        n |= bit << w;
      }
      int row_re = ((n >> 4) << 5) + (n & 15);
      Uri[(size_t)row_re * 256 + k] = f2bf(re[r]);
      Uri[(size_t)(row_re + 16) * 256 + k] = f2bf(im[r]);
    }
  } else if (bid < 1168) {
    // G-builder: Gt[h][n] = sum_w (-1)^{bit_w(n)} Wpost[h][w]  (f16)
    int tid = (bid - 1152) * 256 + t;   // [0,4096)
    int h = tid >> 4;
    int n0 = (tid & 15) << 4;
    float wv8[8];
    #pragma unroll
    for (int w = 0; w < 8; w++) wv8[w] = Wpost[h * 8 + w];
    #pragma unroll
    for (int j = 0; j < 16; j++) {
      int n = n0 + j;
      float sum = 0.f;
      #pragma unroll
      for (int w = 0; w < 8; w++) sum += ((n >> w) & 1) ? -wv8[w] : wv8[w];
      Gt[h * 256 + n] = (_Float16)sum;
    }
  } else {
    int tb = bid - 1168;
    int jt = tb & 31, ht = (tb >> 5) & 7, bb = tb >> 8;
    int tx = t & 31, ty = t >> 5;
    const float* xb = x + (size_t)bb * 1024 * 256;
    #pragma unroll
    for (int i = 0; i < 4; i++) {
      int j = jt * 32 + ty + i * 8;
      smem[(ty + i * 8) * 33 + tx] = xb[(size_t)j * 256 + ht * 32 + tx];
    }
    __syncthreads();
    unsigned short* xTb = xT + (size_t)bb * 256 * 1024;
    #pragma unroll
    for (int i = 0; i < 4; i++) {
      int h = ht * 32 + ty + i * 8;
      xTb[(size_t)h * 1024 + jt * 32 + tx] = f2bf(smem[tx * 33 + ty + i * 8]);
    }
  }
}

// ---------------- gemm1: C = A * Bt^T, tile 128(M) x 64(N), BK=64 (two 32-k panels) ----
// Half the barriers of BK=32 at the same staging-instruction count.
__global__ __launch_bounds__(256)
void gemm1_kernel(const unsigned short* __restrict__ A,
                  const unsigned short* __restrict__ Bt,
                  unsigned short* __restrict__ C,
                  int K, int tilesN, int ldC) {
  __shared__ unsigned short As[2 * 128 * 32];   // 16 KB, [kb][row][32]
  __shared__ unsigned short Bs[2 * 64 * 32];    // 8 KB,  [kb][row][32]
  int rr  = blockIdx.x;
  int im  = rr / tilesN;
  int in_ = rr % tilesN;
  const unsigned short* Ab  = A  + (long long)im * 128 * K;
  const unsigned short* Btb = Bt + (long long)in_ * 64 * K;

  int t = threadIdx.x;
  int wv = t >> 6, lane = t & 63;
  int wm = wv >> 1, wn = wv & 1;
  int l15 = lane & 15, quad = lane >> 4;

  f32x4 acc[4][2] = {};

  for (int kk = 0; kk < K; kk += 64) {
    __syncthreads();
    #pragma unroll
    for (int kb = 0; kb < 2; kb++) {
      #pragma unroll
      for (int q = 0; q < 2; q++) {
        int ch = q * 256 + t;                 // 0..511 -> row = ch>>2, col16 = ch&3
        async_ld16(Ab + (long long)(ch >> 2) * K + kk + kb * 32 + (ch & 3) * 8,
                   &As[kb * 4096 + ch * 8]);
      }
      {
        int ch = t;                           // 0..255 -> row = ch>>2
        async_ld16(Btb + (long long)(ch >> 2) * K + kk + kb * 32 + (ch & 3) * 8,
                   &Bs[kb * 2048 + ch * 8]);
      }
    }
    __syncthreads();
    #pragma unroll
    for (int kb = 0; kb < 2; kb++) {
      bf16x8 af[4], bfr[2];
      #pragma unroll
      for (int mt = 0; mt < 4; mt++)
        af[mt] = *(const bf16x8*)&As[kb * 4096 + (wm * 64 + mt * 16 + l15) * 32 + quad * 8];
      #pragma unroll
      for (int nt = 0; nt < 2; nt++)
        bfr[nt] = *(const bf16x8*)&Bs[kb * 2048 + (wn * 32 + nt * 16 + l15) * 32 + quad * 8];
      #pragma unroll
      for (int mt = 0; mt < 4; mt++)
        #pragma unroll
        for (int nt = 0; nt < 2; nt++)
          acc[mt][nt] = __builtin_amdgcn_mfma_f32_16x16x32_bf16(af[mt], bfr[nt], acc[mt][nt], 0, 0, 0);
    }
  }

  int n0 = in_ * 64;
  #pragma unroll
  for (int mt = 0; mt < 4; mt++) {
    #pragma unroll
    for (int nt = 0; nt < 2; nt++) {
      int colg = n0 + wn * 32 + nt * 16 + l15;
      #pragma unroll
      for (int r = 0; r < 4; r++) {
        int rowg = im * 128 + wm * 64 + mt * 16 + quad * 4 + r;
        C[(size_t)rowg * ldC + colg] = f2bf(acc[mt][nt][r]);
      }
    }
  }
}

// ---------------- qfused: g-GEMM + GELU + angles + P0 + S-GEMM + |S|^2 + out-GEMM ----
// 512 blocks x 256 thr; block owns 32 samples.
// KEY RESTRUCTURE vs previous version: the per-stage B-panels have ZERO cross-wave
// reuse (wave wv stages and reads only rows wv*64 / wv*128), so the LDS round trip
// was pure overhead. All MFMA A/B fragments now load DIRECTLY global->VGPR with a
// register ping-pong (prefetch k8+1 during MFMA of k8); the compiler emits counted
// vmcnt automatically. No intra-stage barriers remain (3 total: gs / P0s / Ts
// cross-wave handoffs). LDS: 32 KB (gs|Ts 16K + P0s 16K) -> 4-blocks/CU capable.
// P0s/Ts panels chunk-XOR-swizzled (chunk ^= (row>>1)&3) to break the 8-way
// bank conflict of [row][64B] b128 reads.
__global__ __launch_bounds__(256)
void qfused_kernel(const unsigned short* __restrict__ xagg,
                   const unsigned short* __restrict__ Wg,
                   const float* __restrict__ bg,
                   const float* __restrict__ Wpre, const float* __restrict__ bpre,
                   const unsigned short* __restrict__ Uri,
                   const _Float16* __restrict__ Gt,
                   const float* __restrict__ bpost,
                   float* __restrict__ out) {
  __shared__ __align__(16) char smemraw[32768];
  unsigned short* gs  = (unsigned short*)smemraw;           // 16 KB [32][256] bf16
  _Float16*       Ts  = (_Float16*)smemraw;                 //   (reused: f16 T panels, swizzled)
  unsigned short* P0s = (unsigned short*)(smemraw + 16384); // 16 KB swizzled panels [8][32][32]

  int t = threadIdx.x;
  int wv = t >> 6, lane = t & 63;
  int l15 = lane & 15, quad = lane >> 4;

  const unsigned short* Ab = xagg + (size_t)blockIdx.x * 32 * 256;

  // ---- stage A: g = GELU(xagg @ Wg^T + bg); wave wv owns cols wv*64..+63 ----
  f32x4 acc[2][4] = {};
  {
    const unsigned short* Ap = Ab + (size_t)l15 * 256 + quad * 8;
    const unsigned short* Wp = Wg + (size_t)(wv * 64 + l15) * 256 + quad * 8;
    bf16x8 af[2][2], wf[2][4];
    #pragma unroll
    for (int mt = 0; mt < 2; mt++) af[0][mt] = *(const bf16x8*)(Ap + mt * 4096);
    #pragma unroll
    for (int nt = 0; nt < 4; nt++) wf[0][nt] = *(const bf16x8*)(Wp + nt * 4096);
    #pragma unroll
    for (int k8 = 0; k8 < 8; k8++) {
      int cur = k8 & 1, nxt = cur ^ 1;
      if (k8 < 7) {
        #pragma unroll
        for (int mt = 0; mt < 2; mt++)
          af[nxt][mt] = *(const bf16x8*)(Ap + (k8 + 1) * 32 + mt * 4096);
        #pragma unroll
        for (int nt = 0; nt < 4; nt++)
          wf[nxt][nt] = *(const bf16x8*)(Wp + (k8 + 1) * 32 + nt * 4096);
      }
      #pragma unroll
      for (int mt = 0; mt < 2; mt++)
        #pragma unroll
        for (int nt = 0; nt < 4; nt++)
          acc[mt][nt] = __builtin_amdgcn_mfma_f32_16x16x32_bf16(af[cur][mt], wf[cur][nt], acc[mt][nt], 0, 0, 0);
    }
  }
  #pragma unroll
  for (int mt = 0; mt < 2; mt++) {
    #pragma unroll
    for (int nt = 0; nt < 4; nt++) {
      int col = wv * 64 + nt * 16 + l15;
      float bgl = bg[col];
      #pragma unroll
      for (int r = 0; r < 4; r++) {
        int row = mt * 16 + quad * 4 + r;
        float v = acc[mt][nt][r] + bgl;
        v = 0.5f * v * (1.0f + fast_erf(v * 0.7071067811865475f));
        gs[row * 256 + col] = f2bf(v);
      }
    }
  }
  // hoist Wpre + bpre into registers (used by angles stage; L2-resident, no LDS copy)
  float4 wp[8];
  #pragma unroll
  for (int w = 0; w < 8; w++) wp[w] = *(const float4*)&Wpre[w * 256 + 4 * lane];
  float bprel = bpre[4 * (lane & 1) + (lane & 2) + ((lane >> 2) & 1)];  // bpre[w(L)]
  __syncthreads();   // gs complete

  // ---- angles + RY product state -> P0s panels; wave wv owns rows wv*8..+7 ----
  // After fold_reduce8, lane L holds the angle-sum for w(L); each lane does ONE
  // tanh/cos/sin for its own w and the (c,s) results are broadcast (was 24
  // redundant wave-wide transcendentals per row).
  #pragma unroll
  for (int rr = 0; rr < 8; rr++) {
    int row = wv * 8 + rr;
    ushort4 gu = *(const ushort4*)&gs[row * 256 + 4 * lane];
    float g0 = bf2f(gu.x), g1 = bf2f(gu.y), g2 = bf2f(gu.z), g3 = bf2f(gu.w);
    float ang[8];
    #pragma unroll
    for (int w = 0; w < 8; w++) {
      float4 w4 = wp[w];
      float a = g0 * w4.x;
      a = fmaf(g1, w4.y, a);
      a = fmaf(g2, w4.z, a);
      a = fmaf(g3, w4.w, a);
      ang[w] = a;
    }
    fold_reduce8(ang, lane);
    float th = (0.5f * PI_F) * fast_tanh(ang[0] + bprel);
    float c = __cosf(th), s = __sinf(th);
    float cw[8], sw[8];
    #pragma unroll
    for (int w = 0; w < 8; w++) {
      int src = ((w >> 2) & 1) | (w & 2) | ((w & 1) << 2);
      cw[w] = __shfl(c, src, 64);
      sw[w] = __shfl(s, src, 64);
    }
    // amp index n = 4*lane + j : bits 0,1 = j ; bits 2..7 = lane bits 0..5
    float pl = 1.f;
    #pragma unroll
    for (int b = 0; b < 6; b++) pl *= ((lane >> b) & 1) ? sw[b + 2] : cw[b + 2];
    ushort4 o;
    o.x = f2bf(pl * cw[0] * cw[1]);
    o.y = f2bf(pl * sw[0] * cw[1]);
    o.z = f2bf(pl * cw[0] * sw[1]);
    o.w = f2bf(pl * sw[0] * sw[1]);
    int j = lane & 7;
    int cswz = (j >> 1) ^ ((row >> 1) & 3);
    *(ushort4*)((char*)P0s + (lane >> 3) * 2048 + row * 64 + cswz * 16 + (j & 1) * 8) = o;
  }
  __syncthreads();   // P0s complete (and all gs reads done -> Ts may reuse arena)

  // ---- stage B: S = P0 @ Uri^T, wave wv owns S-cols wv*128..+127 ----
  // Uri interleaved: nt pair (2p, 2p+1) = re/im of T-col n = (wv*4+p)*16 + l15.
  f32x4 acc1[2][8] = {};
  {
    const unsigned short* Up = Uri + (size_t)(wv * 128 + l15) * 256 + quad * 8;
    const char* Pp = (const char*)P0s + l15 * 64 + (((quad ^ ((l15 >> 1) & 3))) << 4);
    bf16x8 pa[2][2], ua[2][8];
    #pragma unroll
    for (int mt = 0; mt < 2; mt++) pa[0][mt] = *(const bf16x8*)(Pp + mt * 1024);
    #pragma unroll
    for (int nt = 0; nt < 8; nt++) ua[0][nt] = *(const bf16x8*)(Up + nt * 4096);
    #pragma unroll
    for (int k8 = 0; k8 < 8; k8++) {
      int cur = k8 & 1, nxt = cur ^ 1;
      if (k8 < 7) {
        #pragma unroll
        for (int mt = 0; mt < 2; mt++)
          pa[nxt][mt] = *(const bf16x8*)(Pp + (k8 + 1) * 2048 + mt * 1024);
        #pragma unroll
        for (int nt = 0; nt < 8; nt++)
          ua[nxt][nt] = *(const bf16x8*)(Up + (k8 + 1) * 32 + nt * 4096);
      }
      #pragma unroll
      for (int mt = 0; mt < 2; mt++)
        #pragma unroll
        for (int nt = 0; nt < 8; nt++)
          acc1[mt][nt] = __builtin_amdgcn_mfma_f32_16x16x32_bf16(pa[cur][mt], ua[cur][nt], acc1[mt][nt], 0, 0, 0);
    }
  }

  // T = Sre^2 + Sim^2 -> Ts panels (reuses gs arena; swizzled like P0s)
  #pragma unroll
  for (int mt = 0; mt < 2; mt++) {
    #pragma unroll
    for (int p = 0; p < 4; p++) {
      int kb = wv * 2 + (p >> 1);
      int cip = (p & 1) * 16 + l15;
      int ch = cip >> 3;
      #pragma unroll
      for (int r = 0; r < 4; r++) {
        int row = mt * 16 + quad * 4 + r;
        float tre = acc1[mt][2 * p][r], tim = acc1[mt][2 * p + 1][r];
        *(_Float16*)((char*)Ts + kb * 2048 + row * 64 +
                     ((ch ^ ((row >> 1) & 3)) << 4) + (cip & 7) * 2)
            = (_Float16)(tre * tre + tim * tim);
      }
    }
  }
  __syncthreads();   // Ts complete

  // ---- stage C: out = T @ Gt^T + bpost, wave wv owns out-cols wv*64..+63 ----
  f32x4 acc2[2][4] = {};
  {
    const _Float16* Gp = Gt + (size_t)(wv * 64 + l15) * 256 + quad * 8;
    const char* Tp = (const char*)Ts + l15 * 64 + (((quad ^ ((l15 >> 1) & 3))) << 4);
    f16x8 tf[2][2], gf[2][4];
    #pragma unroll
    for (int mt = 0; mt < 2; mt++) tf[0][mt] = *(const f16x8*)(Tp + mt * 1024);
    #pragma unroll
    for (int nt = 0; nt < 4; nt++) gf[0][nt] = *(const f16x8*)(Gp + nt * 4096);
    #pragma unroll
    for (int k8 = 0; k8 < 8; k8++) {
      int cur = k8 & 1, nxt = cur ^ 1;
      if (k8 < 7) {
        #pragma unroll
        for (int mt = 0; mt < 2; mt++)
          tf[nxt][mt] = *(const f16x8*)(Tp + (k8 + 1) * 2048 + mt * 1024);
        #pragma unroll
        for (int nt = 0; nt < 4; nt++)
          gf[nxt][nt] = *(const f16x8*)(Gp + (k8 + 1) * 32 + nt * 4096);
      }
      #pragma unroll
      for (int mt = 0; mt < 2; mt++)
        #pragma unroll
        for (int nt = 0; nt < 4; nt++)
          acc2[mt][nt] = __builtin_amdgcn_mfma_f32_16x16x32_f16(tf[cur][mt], gf[cur][nt], acc2[mt][nt], 0, 0, 0);
    }
  }

  // epilogue: bias + fp32 store with sample un-permute (s = i*16+b -> b*1024+i)
  #pragma unroll
  for (int mt = 0; mt < 2; mt++) {
    #pragma unroll
    for (int nt = 0; nt < 4; nt++) {
      int col = wv * 64 + nt * 16 + l15;
      float bp = bpost[col];
      #pragma unroll
      for (int r = 0; r < 4; r++) {
        int row = mt * 16 + quad * 4 + r;
        int s = blockIdx.x * 32 + row;
        int orow = (s & 15) * 1024 + (s >> 4);
        out[(size_t)orow * 256 + col] = acc2[mt][nt][r] + bp;
      }
    }
  }
}

// ---------------- host launch ----------------
extern "C" void kernel_launch(void* const* d_in, const int* in_sizes, int n_in,
                              void* d_out, int out_size, void* d_ws, size_t ws_size,
                              hipStream_t stream) {
  const float* x     = (const float*)d_in[0];  // (16,1024,256)
  const float* adj   = (const float*)d_in[1];  // (1024,1024)
  const float* Wg    = (const float*)d_in[2];  // (256,256)
  const float* bg    = (const float*)d_in[3];  // (256,)
  const float* Wpre  = (const float*)d_in[4];  // (8,256)
  const float* bpre  = (const float*)d_in[5];  // (8,)
  const float* qw    = (const float*)d_in[6];  // (2,8)
  const float* Wpost = (const float*)d_in[7];  // (256,8)
  const float* bpost = (const float*)d_in[8];  // (256,)
  float* out = (float*)d_out;                  // (16,1024,256)

  char* ws = (char*)d_ws;
  unsigned short* adj_bf  = (unsigned short*)(ws + 0);          // 2 MiB
  unsigned short* Wg_bf   = (unsigned short*)(ws + 2097152);    // 128 KiB
  unsigned short* xT_bf   = (unsigned short*)(ws + 2228224);    // 8 MiB  (4096 x 1024)
  unsigned short* xagg_bf = (unsigned short*)(ws + 10616832);   // 8 MiB  (16384 x 256 view)
  unsigned short* Uri     = (unsigned short*)(ws + 19005440);   // 256 KiB (512 x 256)
  _Float16*       Gt      = (_Float16*)(ws + 19267584);         // 128 KiB (256 x 256)

  // 1) prep: adj/Wg cvt + U-builder (interleaved) + G-builder + x transpose
  prep_kernel<<<5264, 256, 0, stream>>>(adj, adj_bf, Wg, Wg_bf, qw, Uri,
                                        Wpost, Gt, x, xT_bf);

  // 2) xagg = adj @ X'  (1024 x 4096 x 1024, BK=64) -> bf16; 16384x256 rows are s=i*16+b
  gemm1_kernel<<<512, 256, 0, stream>>>(adj_bf, xT_bf, xagg_bf, 1024, 64, 4096);

  // 3) fused: g-GEMM + GELU + angles + P0 (LDS) + S-GEMM + |S|^2 + out-GEMM + un-permute
  qfused_kernel<<<512, 256, 0, stream>>>(xagg_bf, Wg_bf, bg, Wpre, bpre, Uri, Gt, bpost, out);
}

// Round 2
// 142.802 us; speedup vs baseline: 1.0438x; 1.0438x over previous
//
#include <hip/hip_runtime.h>
#include <math.h>

typedef __attribute__((ext_vector_type(8))) short bf16x8;
typedef _Float16 f16x8 __attribute__((ext_vector_type(8)));
typedef __attribute__((ext_vector_type(4))) float f32x4;

#define PI_F 3.14159265358979323846f

__device__ __forceinline__ unsigned short f2bf(float f) {
  unsigned int u = __float_as_uint(f);
  u += 0x7FFFu + ((u >> 16) & 1u);   // RNE to bf16
  return (unsigned short)(u >> 16);
}

__device__ __forceinline__ float bf2f(unsigned short u) {
  return __uint_as_float(((unsigned int)u) << 16);
}

__device__ __forceinline__ void async_ld16(const unsigned short* g, unsigned short* l) {
  __builtin_amdgcn_global_load_lds(
      (const __attribute__((address_space(1))) void*)g,
      (__attribute__((address_space(3))) void*)l,
      16, 0, 0);
}

// fast erf, A&S 7.1.26, |err| <= 1.5e-7 absolute
__device__ __forceinline__ float fast_erf(float x) {
  float a = fabsf(x);
  float t = 1.0f / fmaf(0.3275911f, a, 1.0f);
  float p = t * fmaf(t, fmaf(t, fmaf(t, fmaf(t, 1.061405429f, -1.453152027f),
                                     1.421413741f), -0.284496736f), 0.254829592f);
  float e = __expf(-a * a);
  float r = 1.0f - p * e;
  return copysignf(r, x);
}

__device__ __forceinline__ float fast_tanh(float a) {
  float e = __expf(2.0f * a);
  return 1.0f - 2.0f / (e + 1.0f);
}

// RX on stored basis: XOR-pair (lane-mask ML, register-mask MR); RX matrix symmetric.
template<int ML, int MR>
__device__ __forceinline__ void apply_rx(float re[4], float im[4], float c, float s) {
  float pr[4], pi[4];
  #pragma unroll
  for (int r = 0; r < 4; r++) {
    float vr = re[r ^ MR], vi = im[r ^ MR];
    if (ML) { vr = __shfl_xor(vr, ML, 64); vi = __shfl_xor(vi, ML, 64); }
    pr[r] = vr; pi[r] = vi;
  }
  #pragma unroll
  for (int r = 0; r < 4; r++) {
    re[r] = fmaf(c, re[r],  s * pi[r]);
    im[r] = fmaf(c, im[r], -s * pr[r]);
  }
}

// ---------------- prep: adj/Wg cvt, U-builder (interleaved), G-builder, x transpose ----
// blocks [0,1024): adj cvt; [1024,1088): Wg cvt; [1088,1152): U-builder;
// [1152,1168): G-builder; [1168,5264): x transpose (16,1024,256)->(4096,1024) bf16.
__global__ __launch_bounds__(256)
void prep_kernel(const float* __restrict__ adj, unsigned short* __restrict__ adj_bf,
                 const float* __restrict__ Wg, unsigned short* __restrict__ Wg_bf,
                 const float* __restrict__ qw, unsigned short* __restrict__ Uri,
                 const float* __restrict__ Wpost, _Float16* __restrict__ Gt,
                 const float* __restrict__ x, unsigned short* __restrict__ xT) {
  __shared__ float smem[1056];
  int bid = blockIdx.x, t = threadIdx.x;
  if (bid < 1024) {
    int i = bid * 256 + t;
    float4 v = ((const float4*)adj)[i];
    ushort4 o; o.x = f2bf(v.x); o.y = f2bf(v.y); o.z = f2bf(v.z); o.w = f2bf(v.w);
    ((ushort4*)adj_bf)[i] = o;
  } else if (bid < 1088) {
    int i = (bid - 1024) * 256 + t;
    float4 v = ((const float4*)Wg)[i];
    ushort4 o; o.x = f2bf(v.x); o.y = f2bf(v.y); o.z = f2bf(v.z); o.w = f2bf(v.w);
    ((ushort4*)Wg_bf)[i] = o;
  } else if (bid < 1152) {
    // U-builder: simulate entangler on basis k. CNOT rings deferred (linear maps);
    // layer-2 RX masks = R^-1 e_w; logical index n = R^2 s (rows of R^2 below).
    // Output layout INTERLEAVED by 16-blocks: row (n>>4)*32 + (n&15)      = Ure[n][*]
    //                                         row (n>>4)*32 + 16 + (n&15) = Uim[n][*]
    if (t < 16) { smem[t] = cosf(0.5f * qw[t]); smem[16 + t] = sinf(0.5f * qw[t]); }
    __syncthreads();
    int wv = t >> 6, L = t & 63;
    int k = (bid - 1088) * 4 + wv;
    float re[4], im[4];
    #pragma unroll
    for (int r = 0; r < 4; r++) { re[r] = (r * 64 + L == k) ? 1.f : 0.f; im[r] = 0.f; }
    // layer 1 RX (F = I)
    apply_rx<1, 0>(re, im, smem[0], smem[16]);
    apply_rx<2, 0>(re, im, smem[1], smem[17]);
    apply_rx<4, 0>(re, im, smem[2], smem[18]);
    apply_rx<8, 0>(re, im, smem[3], smem[19]);
    apply_rx<16, 0>(re, im, smem[4], smem[20]);
    apply_rx<32, 0>(re, im, smem[5], smem[21]);
    apply_rx<0, 1>(re, im, smem[6], smem[22]);
    apply_rx<0, 2>(re, im, smem[7], smem[23]);
    // layer 2 RX (F = R): masks R^-1 e_w
    apply_rx<3, 0>(re, im, smem[8], smem[24]);
    apply_rx<6, 0>(re, im, smem[9], smem[25]);
    apply_rx<12, 0>(re, im, smem[10], smem[26]);
    apply_rx<24, 0>(re, im, smem[11], smem[27]);
    apply_rx<48, 0>(re, im, smem[12], smem[28]);
    apply_rx<32, 1>(re, im, smem[13], smem[29]);
    apply_rx<0, 3>(re, im, smem[14], smem[30]);
    apply_rx<3, 2>(re, im, smem[15], smem[31]);
    const int M[8] = {0xAB, 0xFD, 0xFA, 0xF5, 0xEA, 0xD5, 0xAA, 0x55};
    #pragma unroll
    for (int r = 0; r < 4; r++) {
      int n = 0;
      #pragma unroll
      for (int w = 0; w < 8; w++) {
        int bit = (__popc(L & (M[w] & 63)) ^ __popc((r << 6) & M[w])) & 1;
        n |= bit << w;
      }
      int row_re = ((n >> 4) << 5) + (n & 15);
      Uri[(size_t)row_re * 256 + k] = f2bf(re[r]);
      Uri[(size_t)(row_re + 16) * 256 + k] = f2bf(im[r]);
    }
  } else if (bid < 1168) {
    // G-builder: Gt[h][n] = sum_w (-1)^{bit_w(n)} Wpost[h][w]  (f16)
    int tid = (bid - 1152) * 256 + t;   // [0,4096)
    int h = tid >> 4;
    int n0 = (tid & 15) << 4;
    float wv8[8];
    #pragma unroll
    for (int w = 0; w < 8; w++) wv8[w] = Wpost[h * 8 + w];
    #pragma unroll
    for (int j = 0; j < 16; j++) {
      int n = n0 + j;
      float sum = 0.f;
      #pragma unroll
      for (int w = 0; w < 8; w++) sum += ((n >> w) & 1) ? -wv8[w] : wv8[w];
      Gt[h * 256 + n] = (_Float16)sum;
    }
  } else {
    int tb = bid - 1168;
    int jt = tb & 31, ht = (tb >> 5) & 7, bb = tb >> 8;
    int tx = t & 31, ty = t >> 5;
    const float* xb = x + (size_t)bb * 1024 * 256;
    #pragma unroll
    for (int i = 0; i < 4; i++) {
      int j = jt * 32 + ty + i * 8;
      smem[(ty + i * 8) * 33 + tx] = xb[(size_t)j * 256 + ht * 32 + tx];
    }
    __syncthreads();
    unsigned short* xTb = xT + (size_t)bb * 256 * 1024;
    #pragma unroll
    for (int i = 0; i < 4; i++) {
      int h = ht * 32 + ty + i * 8;
      xTb[(size_t)h * 1024 + jt * 32 + tx] = f2bf(smem[tx * 33 + ty + i * 8]);
    }
  }
}

// ---------------- gemm1: C = A * Bt^T, tile 64(M) x 64(N), BK=64 (two 32-k panels) ----
// 1024 blocks -> 4 blocks/CU (16 waves/CU). LDS chunks XOR-swizzled via pre-swizzled
// GLOBAL source (rule: global_load_lds dest must stay linear) so ds_read_b128 frag
// reads are 2-way (free) instead of 8-way conflicted.
__global__ __launch_bounds__(256)
void gemm1_kernel(const unsigned short* __restrict__ A,
                  const unsigned short* __restrict__ Bt,
                  unsigned short* __restrict__ C,
                  int K, int tilesN, int ldC) {
  __shared__ unsigned short As[2 * 64 * 32];   // 8 KB, [kb][row][32] (k-chunks swizzled)
  __shared__ unsigned short Bs[2 * 64 * 32];   // 8 KB
  int rr  = blockIdx.x;
  int im  = rr / tilesN;
  int in_ = rr % tilesN;
  const unsigned short* Ab  = A  + (long long)im * 64 * K;
  const unsigned short* Btb = Bt + (long long)in_ * 64 * K;

  int t = threadIdx.x;
  int wv = t >> 6, lane = t & 63;
  int wm = wv >> 1, wn = wv & 1;
  int l15 = lane & 15, quad = lane >> 4;

  int srow = t >> 2;                        // staging row 0..63
  int skc  = (t & 3) ^ ((srow >> 1) & 3);   // swizzled source k-chunk
  long long sgo = (long long)srow * K + skc * 8;

  f32x4 acc[2][2] = {};

  for (int kk = 0; kk < K; kk += 64) {
    __syncthreads();
    #pragma unroll
    for (int kb = 0; kb < 2; kb++) {
      async_ld16(Ab + sgo + kk + kb * 32, &As[kb * 2048 + t * 8]);
      async_ld16(Btb + sgo + kk + kb * 32, &Bs[kb * 2048 + t * 8]);
    }
    __syncthreads();
    #pragma unroll
    for (int kb = 0; kb < 2; kb++) {
      bf16x8 af[2], bfr[2];
      #pragma unroll
      for (int mt = 0; mt < 2; mt++) {
        int row = wm * 32 + mt * 16 + l15;
        af[mt] = *(const bf16x8*)&As[kb * 2048 + row * 32 + ((quad ^ ((row >> 1) & 3)) * 8)];
      }
      #pragma unroll
      for (int nt = 0; nt < 2; nt++) {
        int row = wn * 32 + nt * 16 + l15;
        bfr[nt] = *(const bf16x8*)&Bs[kb * 2048 + row * 32 + ((quad ^ ((row >> 1) & 3)) * 8)];
      }
      #pragma unroll
      for (int mt = 0; mt < 2; mt++)
        #pragma unroll
        for (int nt = 0; nt < 2; nt++)
          acc[mt][nt] = __builtin_amdgcn_mfma_f32_16x16x32_bf16(af[mt], bfr[nt], acc[mt][nt], 0, 0, 0);
    }
  }

  int n0 = in_ * 64;
  #pragma unroll
  for (int mt = 0; mt < 2; mt++) {
    #pragma unroll
    for (int nt = 0; nt < 2; nt++) {
      int colg = n0 + wn * 32 + nt * 16 + l15;
      #pragma unroll
      for (int r = 0; r < 4; r++) {
        int rowg = im * 64 + wm * 32 + mt * 16 + quad * 4 + r;
        C[(size_t)rowg * ldC + colg] = f2bf(acc[mt][nt][r]);
      }
    }
  }
}

// ---------------- qfused: g-GEMM + GELU + MFMA-angles + P0 + S-GEMM + |S|^2 + out-GEMM ----
// 512 blocks x 512 thr (8 waves); block owns 32 samples. 16 waves/CU (4/SIMD).
// Angles computed as a 32x8x256 MFMA GEMM (Wpre split hi/lo bf16 for f32-weight
// precision): wave wv does K-slice k8=wv -> partials in LDS -> 256 threads do ONE
// tanh/cos/sin each -> P0 build reads c/s via broadcast LDS reads. This removes the
// previous per-row 26-deep dependent shuffle chain. All GEMM operand frags load
// global->VGPR with depth-2 pipelining. 5 barriers total.
// LDS 34 KB: gs|Ts panels 16K (swizzled [8][32][32]) | P0s 16K (partials early) | csw 2K
__global__ __launch_bounds__(512, 4)
void qfused_kernel(const unsigned short* __restrict__ xagg,
                   const unsigned short* __restrict__ Wg,
                   const float* __restrict__ bg,
                   const float* __restrict__ Wpre, const float* __restrict__ bpre,
                   const unsigned short* __restrict__ Uri,
                   const _Float16* __restrict__ Gt,
                   const float* __restrict__ bpost,
                   float* __restrict__ out) {
  __shared__ __align__(16) char smemraw[34816];
  unsigned short* gs  = (unsigned short*)smemraw;            // 16 KB swz panels [8][32][32] bf16
  _Float16*       Ts  = (_Float16*)smemraw;                  //   (reused: f16 T panels, same swz)
  unsigned short* P0s = (unsigned short*)(smemraw + 16384);  // 16 KB swz panels
  float*          prt = (float*)(smemraw + 16384);           //   (early reuse: [8][32][8] f32 partial angles)
  float*          csw = (float*)(smemraw + 32768);           // 2 KB [32][16]: cw[8] | sw[8] per row

  int t = threadIdx.x;
  int wv = t >> 6, lane = t & 63;
  int l15 = lane & 15, quad = lane >> 4;

  const unsigned short* Ab = xagg + (size_t)blockIdx.x * 32 * 256;

  // ---- stage A: g = GELU(xagg @ Wg^T + bg); wave wv owns cols wv*32..+31 ----
  f32x4 acc[2][2] = {};
  {
    const unsigned short* Ap = Ab + (size_t)l15 * 256 + quad * 8;
    const unsigned short* Wp = Wg + (size_t)(wv * 32 + l15) * 256 + quad * 8;
    bf16x8 af[2][2], wf[2][2];
    #pragma unroll
    for (int sl = 0; sl < 2; sl++) {
      #pragma unroll
      for (int mt = 0; mt < 2; mt++) af[sl][mt] = *(const bf16x8*)(Ap + sl * 32 + mt * 4096);
      #pragma unroll
      for (int nt = 0; nt < 2; nt++) wf[sl][nt] = *(const bf16x8*)(Wp + sl * 32 + nt * 4096);
    }
    #pragma unroll
    for (int k8 = 0; k8 < 8; k8++) {
      int cur = k8 & 1;
      #pragma unroll
      for (int mt = 0; mt < 2; mt++)
        #pragma unroll
        for (int nt = 0; nt < 2; nt++)
          acc[mt][nt] = __builtin_amdgcn_mfma_f32_16x16x32_bf16(af[cur][mt], wf[cur][nt], acc[mt][nt], 0, 0, 0);
      if (k8 < 6) {
        #pragma unroll
        for (int mt = 0; mt < 2; mt++) af[cur][mt] = *(const bf16x8*)(Ap + (k8 + 2) * 32 + mt * 4096);
        #pragma unroll
        for (int nt = 0; nt < 2; nt++) wf[cur][nt] = *(const bf16x8*)(Wp + (k8 + 2) * 32 + nt * 4096);
      }
    }
  }
  #pragma unroll
  for (int mt = 0; mt < 2; mt++) {
    #pragma unroll
    for (int nt = 0; nt < 2; nt++) {
      int col = wv * 32 + nt * 16 + l15;
      float bgl = bg[col];
      int c = nt * 16 + l15, chunk = c >> 3, e = c & 7;
      #pragma unroll
      for (int r = 0; r < 4; r++) {
        int row = mt * 16 + quad * 4 + r;
        float v = acc[mt][nt][r] + bgl;
        v = 0.5f * v * (1.0f + fast_erf(v * 0.7071067811865475f));
        *(unsigned short*)((char*)gs + wv * 2048 + row * 64 +
                           ((chunk ^ ((row >> 1) & 3)) << 4) + e * 2) = f2bf(v);
      }
    }
  }
  __syncthreads();   // gs complete

  // ---- angle GEMM slice: wave wv computes K-slice k8=wv of ang = g @ Wpre^T ----
  {
    const float* wrow = Wpre + (size_t)(l15 & 7) * 256 + wv * 32 + quad * 8;
    float4 wa = *(const float4*)wrow;
    float4 wb = *(const float4*)(wrow + 4);
    float v8[8] = {wa.x, wa.y, wa.z, wa.w, wb.x, wb.y, wb.z, wb.w};
    bf16x8 whi, wlo;
    #pragma unroll
    for (int j = 0; j < 8; j++) {
      unsigned short h = f2bf(v8[j]);
      whi[j] = (short)h;
      wlo[j] = (short)f2bf(v8[j] - bf2f(h));
    }
    const char* gp = (const char*)gs + wv * 2048;
    f32x4 aacc[2] = {};
    #pragma unroll
    for (int mt = 0; mt < 2; mt++) {
      int row = mt * 16 + l15;
      bf16x8 ga = *(const bf16x8*)(gp + row * 64 + ((quad ^ ((row >> 1) & 3)) << 4));
      aacc[mt] = __builtin_amdgcn_mfma_f32_16x16x32_bf16(ga, whi, aacc[mt], 0, 0, 0);
      aacc[mt] = __builtin_amdgcn_mfma_f32_16x16x32_bf16(ga, wlo, aacc[mt], 0, 0, 0);
    }
    if (l15 < 8) {
      #pragma unroll
      for (int mt = 0; mt < 2; mt++)
        #pragma unroll
        for (int r = 0; r < 4; r++)
          prt[wv * 256 + (mt * 16 + quad * 4 + r) * 8 + l15] = aacc[mt][r];
    }
  }
  __syncthreads();   // partials complete

  // ---- one transcendental set per (row,w), 256 threads ----
  if (t < 256) {
    float s = 0.f;
    #pragma unroll
    for (int k = 0; k < 8; k++) s += prt[k * 256 + t];
    float th = (0.5f * PI_F) * fast_tanh(s + bpre[t & 7]);
    int row = t >> 3, w = t & 7;
    csw[row * 16 + w] = __cosf(th);
    csw[row * 16 + 8 + w] = __sinf(th);
  }
  __syncthreads();   // csw complete (partials consumed -> P0s region free)

  // ---- RY product state -> P0s panels; wave wv owns rows wv*4..+3 ----
  #pragma unroll
  for (int rr = 0; rr < 4; rr++) {
    int row = wv * 4 + rr;
    float4 c0 = *(const float4*)&csw[row * 16];
    float4 c1 = *(const float4*)&csw[row * 16 + 4];
    float4 s0 = *(const float4*)&csw[row * 16 + 8];
    float4 s1 = *(const float4*)&csw[row * 16 + 12];
    float cw[8] = {c0.x, c0.y, c0.z, c0.w, c1.x, c1.y, c1.z, c1.w};
    float sw[8] = {s0.x, s0.y, s0.z, s0.w, s1.x, s1.y, s1.z, s1.w};
    // amp index n = 4*lane + j : bits 0,1 = j ; bits 2..7 = lane bits 0..5
    float pl = 1.f;
    #pragma unroll
    for (int b = 0; b < 6; b++) pl *= ((lane >> b) & 1) ? sw[b + 2] : cw[b + 2];
    ushort4 o;
    o.x = f2bf(pl * cw[0] * cw[1]);
    o.y = f2bf(pl * sw[0] * cw[1]);
    o.z = f2bf(pl * cw[0] * sw[1]);
    o.w = f2bf(pl * sw[0] * sw[1]);
    int jj = lane & 7;
    int cswz = (jj >> 1) ^ ((row >> 1) & 3);
    *(ushort4*)((char*)P0s + (lane >> 3) * 2048 + row * 64 + cswz * 16 + (jj & 1) * 8) = o;
  }
  __syncthreads();   // P0s complete

  // ---- stage B: S = P0 @ Uri^T; wave wv owns S-cols wv*64..+63 ----
  // Uri interleaved: nt pair (2p,2p+1) = re/im of T-col n = (wv*2+p)*16 + l15.
  f32x4 acc1[2][4] = {};
  {
    const unsigned short* Up = Uri + (size_t)(wv * 64 + l15) * 256 + quad * 8;
    const char* Pp = (const char*)P0s + l15 * 64 + ((quad ^ ((l15 >> 1) & 3)) << 4);
    bf16x8 pa[2][2], ua[2][4];
    #pragma unroll
    for (int sl = 0; sl < 2; sl++) {
      #pragma unroll
      for (int mt = 0; mt < 2; mt++) pa[sl][mt] = *(const bf16x8*)(Pp + sl * 2048 + mt * 1024);
      #pragma unroll
      for (int nt = 0; nt < 4; nt++) ua[sl][nt] = *(const bf16x8*)(Up + sl * 32 + nt * 4096);
    }
    #pragma unroll
    for (int k8 = 0; k8 < 8; k8++) {
      int cur = k8 & 1;
      #pragma unroll
      for (int mt = 0; mt < 2; mt++)
        #pragma unroll
        for (int nt = 0; nt < 4; nt++)
          acc1[mt][nt] = __builtin_amdgcn_mfma_f32_16x16x32_bf16(pa[cur][mt], ua[cur][nt], acc1[mt][nt], 0, 0, 0);
      if (k8 < 6) {
        #pragma unroll
        for (int mt = 0; mt < 2; mt++) pa[cur][mt] = *(const bf16x8*)(Pp + (k8 + 2) * 2048 + mt * 1024);
        #pragma unroll
        for (int nt = 0; nt < 4; nt++) ua[cur][nt] = *(const bf16x8*)(Up + (k8 + 2) * 32 + nt * 4096);
      }
    }
  }

  // T = Sre^2 + Sim^2 -> Ts panels (reuses gs arena; same swizzle)
  #pragma unroll
  for (int mt = 0; mt < 2; mt++) {
    #pragma unroll
    for (int p = 0; p < 2; p++) {
      int c = p * 16 + l15, chunk = c >> 3, e = c & 7;
      #pragma unroll
      for (int r = 0; r < 4; r++) {
        int row = mt * 16 + quad * 4 + r;
        float tre = acc1[mt][2 * p][r], tim = acc1[mt][2 * p + 1][r];
        *(_Float16*)((char*)Ts + wv * 2048 + row * 64 +
                     ((chunk ^ ((row >> 1) & 3)) << 4) + e * 2)
            = (_Float16)(tre * tre + tim * tim);
      }
    }
  }
  __syncthreads();   // Ts complete

  // ---- stage C: out = T @ Gt^T + bpost; wave wv owns out-cols wv*32..+31 ----
  f32x4 acc2[2][2] = {};
  {
    const _Float16* Gp = Gt + (size_t)(wv * 32 + l15) * 256 + quad * 8;
    const char* Tp = (const char*)Ts + l15 * 64 + ((quad ^ ((l15 >> 1) & 3)) << 4);
    f16x8 tf[2][2], gf[2][2];
    #pragma unroll
    for (int sl = 0; sl < 2; sl++) {
      #pragma unroll
      for (int mt = 0; mt < 2; mt++) tf[sl][mt] = *(const f16x8*)(Tp + sl * 2048 + mt * 1024);
      #pragma unroll
      for (int nt = 0; nt < 2; nt++) gf[sl][nt] = *(const f16x8*)(Gp + sl * 32 + nt * 4096);
    }
    #pragma unroll
    for (int k8 = 0; k8 < 8; k8++) {
      int cur = k8 & 1;
      #pragma unroll
      for (int mt = 0; mt < 2; mt++)
        #pragma unroll
        for (int nt = 0; nt < 2; nt++)
          acc2[mt][nt] = __builtin_amdgcn_mfma_f32_16x16x32_f16(tf[cur][mt], gf[cur][nt], acc2[mt][nt], 0, 0, 0);
      if (k8 < 6) {
        #pragma unroll
        for (int mt = 0; mt < 2; mt++) tf[cur][mt] = *(const f16x8*)(Tp + (k8 + 2) * 2048 + mt * 1024);
        #pragma unroll
        for (int nt = 0; nt < 2; nt++) gf[cur][nt] = *(const f16x8*)(Gp + (k8 + 2) * 32 + nt * 4096);
      }
    }
  }

  // epilogue: bias + fp32 store with sample un-permute (s = i*16+b -> b*1024+i)
  #pragma unroll
  for (int mt = 0; mt < 2; mt++) {
    #pragma unroll
    for (int nt = 0; nt < 2; nt++) {
      int col = wv * 32 + nt * 16 + l15;
      float bp = bpost[col];
      #pragma unroll
      for (int r = 0; r < 4; r++) {
        int row = mt * 16 + quad * 4 + r;
        int s = blockIdx.x * 32 + row;
        int orow = (s & 15) * 1024 + (s >> 4);
        out[(size_t)orow * 256 + col] = acc2[mt][nt][r] + bp;
      }
    }
  }
}

// ---------------- host launch ----------------
extern "C" void kernel_launch(void* const* d_in, const int* in_sizes, int n_in,
                              void* d_out, int out_size, void* d_ws, size_t ws_size,
                              hipStream_t stream) {
  const float* x     = (const float*)d_in[0];  // (16,1024,256)
  const float* adj   = (const float*)d_in[1];  // (1024,1024)
  const float* Wg    = (const float*)d_in[2];  // (256,256)
  const float* bg    = (const float*)d_in[3];  // (256,)
  const float* Wpre  = (const float*)d_in[4];  // (8,256)
  const float* bpre  = (const float*)d_in[5];  // (8,)
  const float* qw    = (const float*)d_in[6];  // (2,8)
  const float* Wpost = (const float*)d_in[7];  // (256,8)
  const float* bpost = (const float*)d_in[8];  // (256,)
  float* out = (float*)d_out;                  // (16,1024,256)

  char* ws = (char*)d_ws;
  unsigned short* adj_bf  = (unsigned short*)(ws + 0);          // 2 MiB
  unsigned short* Wg_bf   = (unsigned short*)(ws + 2097152);    // 128 KiB
  unsigned short* xT_bf   = (unsigned short*)(ws + 2228224);    // 8 MiB  (4096 x 1024)
  unsigned short* xagg_bf = (unsigned short*)(ws + 10616832);   // 8 MiB  (16384 x 256 view)
  unsigned short* Uri     = (unsigned short*)(ws + 19005440);   // 256 KiB (512 x 256)
  _Float16*       Gt      = (_Float16*)(ws + 19267584);         // 128 KiB (256 x 256)

  // 1) prep: adj/Wg cvt + U-builder (interleaved) + G-builder + x transpose
  prep_kernel<<<5264, 256, 0, stream>>>(adj, adj_bf, Wg, Wg_bf, qw, Uri,
                                        Wpost, Gt, x, xT_bf);

  // 2) xagg = adj @ X'  (1024 x 4096 x 1024, tile 64x64) -> bf16; rows are s=i*16+b
  gemm1_kernel<<<1024, 256, 0, stream>>>(adj_bf, xT_bf, xagg_bf, 1024, 64, 4096);

  // 3) fused: g-GEMM + GELU + MFMA-angles + P0 (LDS) + S-GEMM + |S|^2 + out-GEMM
  qfused_kernel<<<512, 512, 0, stream>>>(xagg_bf, Wg_bf, bg, Wpre, bpre, Uri, Gt, bpost, out);
}